// Round 4
// baseline (119.440 us; speedup 1.0000x reference)
//
#include <hip/hip_runtime.h>
#include <hip/hip_bf16.h>

#define T_LEN 200
#define MT    13          // ceil(200/16)

typedef __bf16 bf16x8 __attribute__((ext_vector_type(8)));
typedef __bf16 bf16x4 __attribute__((ext_vector_type(4)));
typedef float  f32x4  __attribute__((ext_vector_type(4)));

#if __has_builtin(__builtin_amdgcn_mfma_f32_16x16x16_bf16)
#define MFMA16(a, b, c) __builtin_amdgcn_mfma_f32_16x16x16_bf16((a), (b), (c), 0, 0, 0)
#elif __has_builtin(__builtin_amdgcn_mfma_f32_16x16x16bf16_1k)
#define MFMA16(a, b, c) __builtin_amdgcn_mfma_f32_16x16x16bf16_1k((a), (b), (c), 0, 0, 0)
#else
static __device__ __forceinline__ f32x4 mfma16_asm(bf16x4 a, bf16x4 b, f32x4 c) {
  asm("v_mfma_f32_16x16x16_bf16 %0, %1, %2, %0" : "+v"(c) : "v"(a), "v"(b));
  return c;
}
#define MFMA16(a, b, c) mfma16_asm((a), (b), (c))
#endif

#define MFMA32(a, b, c) __builtin_amdgcn_mfma_f32_16x16x32_bf16((a), (b), (c), 0, 0, 0)

// d_ws layout (bytes):
//   [0,      8192)  w1acP : bf16, per-lane A-frag order [lane][frag(8)][e(8)]  (W1a+W1c)
//   [8192,  16384)  w1dP  : bf16, same order                                   (W1d)
//   [16384, 20480)  w2P   : bf16, per-lane B-frag order [lane][frag(8)][i(4)]
//   [20480, 36864)  wdiffT: f32 [j(64)][d(64)]                                 (W1b-W1c)

__global__ __launch_bounds__(256) void prep_kernel(
    const float* __restrict__ W1g, const float* __restrict__ W2g,
    unsigned char* __restrict__ ws)
{
  const int idx = blockIdx.x * 256 + threadIdx.x;   // 0..4095
  unsigned short* w1acP = (unsigned short*)(ws);
  unsigned short* w1dP  = (unsigned short*)(ws + 8192);
  unsigned short* w2P   = (unsigned short*)(ws + 16384);
  float*          wdifT = (float*)(ws + 20480);
  {
    // A-fragment pack: lane l=(g,r), frag f=(jt,kc), elem e
    int l = idx >> 6, q = idx & 63;
    int f = q >> 3, e = q & 7;
    int jt = f >> 1, kc = f & 1;
    int g = l >> 4, r = l & 15;
    int j = jt * 16 + r;
    int d = kc * 32 + g * 8 + e;
    float ac = W1g[d * 64 + j] + W1g[(128 + d) * 64 + j];
    float dd = W1g[(192 + d) * 64 + j];
    __bf16 acb = (__bf16)ac, ddb = (__bf16)dd;
    w1acP[l * 64 + f * 8 + e] = *(unsigned short*)&acb;
    w1dP [l * 64 + f * 8 + e] = *(unsigned short*)&ddb;
  }
  if (idx < 2048) {
    // layer-2 B-fragment pack: frag f = nt*4+c, elem i
    int l = idx >> 5, q = idx & 31;
    int f = q >> 2, i = q & 3;
    int nt = f >> 2, c = f & 3;
    int g = l >> 4, r = l & 15;
    __bf16 v = (__bf16)W2g[(c * 16 + g * 4 + i) * 32 + nt * 16 + r];
    w2P[l * 32 + f * 4 + i] = *(unsigned short*)&v;
  }
  {
    int j = idx & 63, d = idx >> 6;
    wdifT[j * 64 + d] = W1g[(64 + d) * 64 + j] - W1g[(128 + d) * 64 + j];
  }
}

__device__ __forceinline__ void loadA(const float* __restrict__ behB, int t, int kb,
                                      f32x4* x) {
  if (t < T_LEN) {
    const float* p = behB + (size_t)t * 64 + kb;
    x[0] = *(const f32x4*)p;
    x[1] = *(const f32x4*)(p + 4);
    x[2] = *(const f32x4*)(p + 32);
    x[3] = *(const f32x4*)(p + 36);
  } else {
    x[0] = f32x4{0.f, 0.f, 0.f, 0.f};
    x[1] = f32x4{0.f, 0.f, 0.f, 0.f};
    x[2] = f32x4{0.f, 0.f, 0.f, 0.f};
    x[3] = f32x4{0.f, 0.f, 0.f, 0.f};
  }
}

__global__ __launch_bounds__(256, 4) void lau_kernel(
    const float* __restrict__ behG, const float* __restrict__ candG,
    const int*  __restrict__ maskG,
    const float* __restrict__ b1g, const float* __restrict__ a1g,
    const float* __restrict__ b2g, const float* __restrict__ a2g,
    const float* __restrict__ W3g,
    const unsigned char* __restrict__ ws,
    float* __restrict__ outG)
{
  const int tid  = threadIdx.x;
  const int lane = tid & 63;
  const int wv   = tid >> 6;
  const int b    = blockIdx.x * 4 + wv;
  const int r    = lane & 15;
  const int g    = lane >> 4;
  const int kb   = g * 8;

  const unsigned short* w1acP = (const unsigned short*)(ws);
  const unsigned short* w1dP  = (const unsigned short*)(ws + 8192);
  const unsigned short* w2P   = (const unsigned short*)(ws + 16384);
  const float*          wdifT = (const float*)(ws + 20480);

  // mask dtype detection (wave-uniform)
  const bool boolmask = (__ballot(((const unsigned int*)maskG)[lane] > 1u) != 0ull);

  // candidate chunks for this lane's d-columns (broadcast-friendly loads)
  const float* candB = candG + (size_t)b * 64;
  const f32x4 c0a = *(const f32x4*)(candB + kb);
  const f32x4 c0b = *(const f32x4*)(candB + kb + 4);
  const f32x4 c1a = *(const f32x4*)(candB + kb + 32);
  const f32x4 c1b = *(const f32x4*)(candB + kb + 36);

  // loop-invariant layer-1 A-fragments: W1eff^T = (W1a+W1c) + cand_d * W1d
  bf16x8 A1[4][2];
#pragma unroll
  for (int f = 0; f < 8; ++f) {
    const int jt = f >> 1, kc = f & 1;
    bf16x8 ac = *(const bf16x8*)(w1acP + lane * 64 + f * 8);
    bf16x8 dd = *(const bf16x8*)(w1dP  + lane * 64 + f * 8);
    f32x4 cA = kc ? c1a : c0a;
    f32x4 cB = kc ? c1b : c0b;
    bf16x8 o;
#pragma unroll
    for (int e = 0; e < 4; ++e) {
      o[e]     = (__bf16)((float)ac[e]     + cA[e] * (float)dd[e]);
      o[4 + e] = (__bf16)((float)ac[4 + e] + cB[e] * (float)dd[4 + e]);
    }
    A1[jt][kc] = o;
  }

  // layer-2 B fragments (pre-packed)
  bf16x4 B2f[8];
#pragma unroll
  for (int f = 0; f < 8; ++f)
    B2f[f] = *(const bf16x4*)(w2P + lane * 32 + f * 4);

  // exact f32 bias: b1 + cand @ (W1b - W1c)
  float biasv = b1g[lane];
  {
    const float* wdrow = wdifT + lane * 64;
#pragma unroll
    for (int d4 = 0; d4 < 16; ++d4) {
      f32x4 wd = *(const f32x4*)(wdrow + d4 * 4);
      f32x4 cd = *(const f32x4*)(candB + d4 * 4);
      biasv += wd[0] * cd[0] + wd[1] * cd[1] + wd[2] * cd[2] + wd[3] * cd[3];
    }
  }
  f32x4 bj4[4];
#pragma unroll
  for (int jt = 0; jt < 4; ++jt)
#pragma unroll
    for (int i = 0; i < 4; ++i)
      bj4[jt][i] = __shfl(biasv, jt * 16 + g * 4 + i);

  const float al1 = a1g[0];
  const float al2 = a2g[0];
  const float b2v0 = b2g[r],  b2v1 = b2g[16 + r];
  const float w3v0 = W3g[r],  w3v1 = W3g[16 + r];
  const f32x4 cinit0 = {b2v0, b2v0, b2v0, b2v0};
  const f32x4 cinit1 = {b2v1, b2v1, b2v1, b2v1};

  const float* behB = behG + (size_t)b * T_LEN * 64;
  const unsigned char* maskB8 = (const unsigned char*)maskG + (size_t)b * T_LEN;
  const int* maskB32 = maskG + (size_t)b * T_LEN;

  float mrun = -__builtin_inff();
  float srun = 0.f;
  f32x4 o0 = {0,0,0,0}, o1 = {0,0,0,0}, o2 = {0,0,0,0}, o3 = {0,0,0,0};

  f32x4 xn[4];
  loadA(behB, r, kb, xn);
  int mc = boolmask ? (int)maskB8[r] : maskB32[r];
  int mn = 0;

#pragma unroll 1
  for (int mt = 0; mt < MT; ++mt) {
    // convert current tile to bf16 fragments (frees xn for prefetch)
    bf16x8 ab0, ab1;
#pragma unroll
    for (int i = 0; i < 4; ++i) {
      ab0[i]     = (__bf16)xn[0][i];
      ab0[4 + i] = (__bf16)xn[1][i];
      ab1[i]     = (__bf16)xn[2][i];
      ab1[4 + i] = (__bf16)xn[3][i];
    }
    // prefetch next tile immediately -> full iteration of latency slack
    if (mt + 1 < MT) {
      int tn = (mt + 1) * 16 + r;
      loadA(behB, tn, kb, xn);
      mn = (tn < T_LEN) ? (boolmask ? (int)maskB8[tn] : maskB32[tn]) : 0;
    }

    // ---- layer 1 (swapped: D[j][t]), bias via MFMA C-in ----
    bf16x4 a2f[4];
#pragma unroll
    for (int jt = 0; jt < 4; ++jt) {
      f32x4 acc = MFMA32(A1[jt][0], ab0, bj4[jt]);
      acc = MFMA32(A1[jt][1], ab1, acc);
#pragma unroll
      for (int i = 0; i < 4; ++i) {
        float h = acc[i];
        h = (h >= 0.f) ? h : al1 * h;
        a2f[jt][i] = (__bf16)h;
      }
    }

    // ---- layer 2: 8x mfma 16x16x16, bias via C-init ----
    f32x4 acc20 = cinit0, acc21 = cinit1;
#pragma unroll
    for (int c = 0; c < 4; ++c) acc20 = MFMA16(a2f[c], B2f[c], acc20);
#pragma unroll
    for (int c = 0; c < 4; ++c) acc21 = MFMA16(a2f[c], B2f[4 + c], acc21);

    // ---- layer 3 dot + reduce over j2 ----
    f32x4 q;
#pragma unroll
    for (int i = 0; i < 4; ++i) {
      float h0 = acc20[i]; h0 = (h0 >= 0.f) ? h0 : al2 * h0;
      float h1 = acc21[i]; h1 = (h1 >= 0.f) ? h1 : al2 * h1;
      q[i] = h0 * w3v0 + h1 * w3v1;
    }
#pragma unroll
    for (int off = 1; off < 16; off <<= 1)
#pragma unroll
      for (int i = 0; i < 4; ++i) q[i] += __shfl_xor(q[i], off);
    // q[i] = logit[t = mt*16 + g*4 + i], replicated across r

    // route logit for t=r to this lane
    const int srcl = (r >> 2) << 4;
    float f0 = __shfl(q[0], srcl);
    float f1 = __shfl(q[1], srcl);
    float f2 = __shfl(q[2], srcl);
    float f3 = __shfl(q[3], srcl);
    float q01 = (r & 1) ? f1 : f0;
    float q23 = (r & 1) ? f3 : f2;
    float qt  = (r & 2) ? q23 : q01;

    const bool valid = ((mt * 16 + r) < T_LEN) && (mc != 0);
    float lvt = valid ? qt : -__builtin_inff();
    float tm = lvt;
#pragma unroll
    for (int off = 1; off < 16; off <<= 1) tm = fmaxf(tm, __shfl_xor(tm, off));

    // defer-max: rescale only when tile max moved by > 8
    if (tm > mrun + 8.f) {
      float fs = __expf(mrun - tm);
      srun *= fs;
#pragma unroll
      for (int i = 0; i < 4; ++i) { o0[i] *= fs; o1[i] *= fs; o2[i] *= fs; o3[i] *= fs; }
      mrun = tm;
    }
    float et = valid ? __expf(lvt - mrun) : 0.f;
    srun += et;
#pragma unroll
    for (int i = 0; i < 4; ++i) {
      o0[i] += et * (float)ab0[i];
      o1[i] += et * (float)ab0[4 + i];
      o2[i] += et * (float)ab1[i];
      o3[i] += et * (float)ab1[4 + i];
    }
    mc = mn;
  }

  // ---- epilogue: reduce over r (16 t-rows per slot) ----
#pragma unroll
  for (int off = 1; off < 16; off <<= 1) {
#pragma unroll
    for (int i = 0; i < 4; ++i) {
      o0[i] += __shfl_xor(o0[i], off);
      o1[i] += __shfl_xor(o1[i], off);
      o2[i] += __shfl_xor(o2[i], off);
      o3[i] += __shfl_xor(o3[i], off);
    }
    srun += __shfl_xor(srun, off);
  }
  if (r == 0) {
    float inv = 1.f / srun;
    float* po = outG + (size_t)b * 64 + kb;
#pragma unroll
    for (int i = 0; i < 4; ++i) {
      o0[i] *= inv; o1[i] *= inv; o2[i] *= inv; o3[i] *= inv;
    }
    *(f32x4*)(po)      = o0;
    *(f32x4*)(po + 4)  = o1;
    *(f32x4*)(po + 32) = o2;
    *(f32x4*)(po + 36) = o3;
  }
}

extern "C" void kernel_launch(void* const* d_in, const int* in_sizes, int n_in,
                              void* d_out, int out_size, void* d_ws, size_t ws_size,
                              hipStream_t stream) {
  (void)n_in; (void)ws_size; (void)out_size;
  const float* beh  = (const float*)d_in[0];
  const float* cand = (const float*)d_in[1];
  const int*   mask = (const int*)d_in[2];
  const float* W1   = (const float*)d_in[3];
  const float* b1   = (const float*)d_in[4];
  const float* a1   = (const float*)d_in[5];
  const float* W2   = (const float*)d_in[6];
  const float* b2   = (const float*)d_in[7];
  const float* a2   = (const float*)d_in[8];
  const float* W3   = (const float*)d_in[9];
  // d_in[10] (b3): uniform additive bias cancels in softmax

  unsigned char* ws = (unsigned char*)d_ws;
  prep_kernel<<<16, 256, 0, stream>>>(W1, W2, ws);

  int B = in_sizes[1] / 64;   // 4096
  int grid = B / 4;           // one wave per batch row
  lau_kernel<<<grid, 256, 0, stream>>>(beh, cand, mask, b1, a1, b2, a2, W3,
                                       ws, (float*)d_out);
}

// Round 5
// 92.492 us; speedup vs baseline: 1.2914x; 1.2914x over previous
//
#include <hip/hip_runtime.h>
#include <hip/hip_bf16.h>

#define T_LEN 200
#define MT    13          // ceil(200/16)

typedef __bf16 bf16x8 __attribute__((ext_vector_type(8)));
typedef __bf16 bf16x4 __attribute__((ext_vector_type(4)));
typedef float  f32x4  __attribute__((ext_vector_type(4)));

#if __has_builtin(__builtin_amdgcn_mfma_f32_16x16x16_bf16)
#define MFMA16(a, b, c) __builtin_amdgcn_mfma_f32_16x16x16_bf16((a), (b), (c), 0, 0, 0)
#elif __has_builtin(__builtin_amdgcn_mfma_f32_16x16x16bf16_1k)
#define MFMA16(a, b, c) __builtin_amdgcn_mfma_f32_16x16x16bf16_1k((a), (b), (c), 0, 0, 0)
#else
static __device__ __forceinline__ f32x4 mfma16_asm(bf16x4 a, bf16x4 b, f32x4 c) {
  asm("v_mfma_f32_16x16x16_bf16 %0, %1, %2, %0" : "+v"(c) : "v"(a), "v"(b));
  return c;
}
#define MFMA16(a, b, c) mfma16_asm((a), (b), (c))
#endif

#define MFMA32(a, b, c) __builtin_amdgcn_mfma_f32_16x16x32_bf16((a), (b), (c), 0, 0, 0)

// d_ws layout (bytes):
//   [0,      8192)  w1acP : bf16 per-lane A-frag order [lane][frag(8)][e(8)]  (W1a+W1c)
//   [8192,  16384)  w1dP  : bf16 same order                                   (W1d)
//   [16384, 20480)  w2P   : bf16 per-lane B-frag order [lane][frag(8)][i(4)]
//   [20480, 36864)  wdiffT: f32 [j(64)][d(64)]                                (W1b-W1c)

__global__ __launch_bounds__(256) void prep_kernel(
    const float* __restrict__ W1g, const float* __restrict__ W2g,
    unsigned char* __restrict__ ws)
{
  const int idx = blockIdx.x * 256 + threadIdx.x;   // 0..4095
  unsigned short* w1acP = (unsigned short*)(ws);
  unsigned short* w1dP  = (unsigned short*)(ws + 8192);
  unsigned short* w2P   = (unsigned short*)(ws + 16384);
  float*          wdifT = (float*)(ws + 20480);
  {
    int l = idx >> 6, q = idx & 63;
    int f = q >> 3, e = q & 7;
    int jt = f >> 1, kc = f & 1;
    int g = l >> 4, r = l & 15;
    int j = jt * 16 + r;
    int d = kc * 32 + g * 8 + e;
    float ac = W1g[d * 64 + j] + W1g[(128 + d) * 64 + j];
    float dd = W1g[(192 + d) * 64 + j];
    __bf16 acb = (__bf16)ac, ddb = (__bf16)dd;
    w1acP[l * 64 + f * 8 + e] = *(unsigned short*)&acb;
    w1dP [l * 64 + f * 8 + e] = *(unsigned short*)&ddb;
  }
  if (idx < 2048) {
    int l = idx >> 5, q = idx & 31;
    int f = q >> 2, i = q & 3;
    int nt = f >> 2, c = f & 3;
    int g = l >> 4, r = l & 15;
    __bf16 v = (__bf16)W2g[(c * 16 + g * 4 + i) * 32 + nt * 16 + r];
    w2P[l * 32 + f * 4 + i] = *(unsigned short*)&v;
  }
  {
    int j = idx & 63, d = idx >> 6;
    wdifT[j * 64 + d] = W1g[(64 + d) * 64 + j] - W1g[(128 + d) * 64 + j];
  }
}

__device__ __forceinline__ void loadA(const float* __restrict__ behB, int t, int kb,
                                      f32x4 (&x)[4]) {
  if (t < T_LEN) {
    const float* p = behB + (size_t)t * 64 + kb;
    x[0] = *(const f32x4*)p;
    x[1] = *(const f32x4*)(p + 4);
    x[2] = *(const f32x4*)(p + 32);
    x[3] = *(const f32x4*)(p + 36);
  } else {
    x[0] = f32x4{0.f, 0.f, 0.f, 0.f};
    x[1] = f32x4{0.f, 0.f, 0.f, 0.f};
    x[2] = f32x4{0.f, 0.f, 0.f, 0.f};
    x[3] = f32x4{0.f, 0.f, 0.f, 0.f};
  }
}

__global__ __launch_bounds__(256, 3) void lau_kernel(
    const float* __restrict__ behG, const float* __restrict__ candG,
    const int*  __restrict__ maskG,
    const float* __restrict__ b1g, const float* __restrict__ a1g,
    const float* __restrict__ b2g, const float* __restrict__ a2g,
    const float* __restrict__ W3g,
    const unsigned char* __restrict__ ws,
    float* __restrict__ outG)
{
  const int tid  = threadIdx.x;
  const int lane = tid & 63;
  const int wv   = tid >> 6;
  const int b    = blockIdx.x * 4 + wv;
  const int r    = lane & 15;
  const int g    = lane >> 4;
  const int kb   = g * 8;

  const unsigned short* w1acP = (const unsigned short*)(ws);
  const unsigned short* w1dP  = (const unsigned short*)(ws + 8192);
  const unsigned short* w2P   = (const unsigned short*)(ws + 16384);
  const float*          wdifT = (const float*)(ws + 20480);

  const bool boolmask = (__ballot(((const unsigned int*)maskG)[lane] > 1u) != 0ull);

  const float* candB = candG + (size_t)b * 64;
  const f32x4 c0a = *(const f32x4*)(candB + kb);
  const f32x4 c0b = *(const f32x4*)(candB + kb + 4);
  const f32x4 c1a = *(const f32x4*)(candB + kb + 32);
  const f32x4 c1b = *(const f32x4*)(candB + kb + 36);

  // loop-invariant layer-1 A-fragments: W1eff^T = (W1a+W1c) + cand_d * W1d
  bf16x8 A1[4][2];
#pragma unroll
  for (int f = 0; f < 8; ++f) {
    const int jt = f >> 1, kc = f & 1;
    bf16x8 ac = *(const bf16x8*)(w1acP + lane * 64 + f * 8);
    bf16x8 dd = *(const bf16x8*)(w1dP  + lane * 64 + f * 8);
    f32x4 cA = kc ? c1a : c0a;
    f32x4 cB = kc ? c1b : c0b;
    bf16x8 o;
#pragma unroll
    for (int e = 0; e < 4; ++e) {
      o[e]     = (__bf16)((float)ac[e]     + cA[e] * (float)dd[e]);
      o[4 + e] = (__bf16)((float)ac[4 + e] + cB[e] * (float)dd[4 + e]);
    }
    A1[jt][kc] = o;
  }

  bf16x4 B2f[8];
#pragma unroll
  for (int f = 0; f < 8; ++f)
    B2f[f] = *(const bf16x4*)(w2P + lane * 32 + f * 4);

  // exact f32 bias: b1 + cand @ (W1b - W1c)
  float biasv = b1g[lane];
  {
    const float* wdrow = wdifT + lane * 64;
#pragma unroll
    for (int d4 = 0; d4 < 16; ++d4) {
      f32x4 wd = *(const f32x4*)(wdrow + d4 * 4);
      f32x4 cd = *(const f32x4*)(candB + d4 * 4);
      biasv += wd[0] * cd[0] + wd[1] * cd[1] + wd[2] * cd[2] + wd[3] * cd[3];
    }
  }
  f32x4 bj4[4];
#pragma unroll
  for (int jt = 0; jt < 4; ++jt)
#pragma unroll
    for (int i = 0; i < 4; ++i)
      bj4[jt][i] = __shfl(biasv, jt * 16 + g * 4 + i);

  const float al1 = a1g[0];
  const float al2 = a2g[0];
  const float b2v0 = b2g[r],  b2v1 = b2g[16 + r];
  const float w3v0 = W3g[r],  w3v1 = W3g[16 + r];
  const f32x4 cinit0 = {b2v0, b2v0, b2v0, b2v0};
  const f32x4 cinit1 = {b2v1, b2v1, b2v1, b2v1};

  const float* behB = behG + (size_t)b * T_LEN * 64;
  const unsigned char* maskB8 = (const unsigned char*)maskG + (size_t)b * T_LEN;
  const int* maskB32 = maskG + (size_t)b * T_LEN;

  // per-lane online-softmax state (lane owns t = mt*16 + r)
  float mrun = -__builtin_inff();
  float srun = 0.f;
  f32x4 o0 = {0,0,0,0}, o1 = {0,0,0,0}, o2 = {0,0,0,0}, o3 = {0,0,0,0};

  // depth-2 prefetch: ping-pong buffers
  f32x4 xa[4], xb[4];
  int ma, mb;
  loadA(behB, r, kb, xa);
  loadA(behB, 16 + r, kb, xb);
  ma = boolmask ? (int)maskB8[r] : maskB32[r];
  mb = (16 + r < T_LEN) ? (boolmask ? (int)maskB8[16 + r] : maskB32[16 + r]) : 0;

  auto step = [&](f32x4 (&xc)[4], int mcv, int mt, f32x4 (&xp)[4], int& mpv, bool pf) {
    // convert current tile to bf16 fragments (frees xc regs for prefetch)
    bf16x8 ab0, ab1;
#pragma unroll
    for (int i = 0; i < 4; ++i) {
      ab0[i]     = (__bf16)xc[0][i];
      ab0[4 + i] = (__bf16)xc[1][i];
      ab1[i]     = (__bf16)xc[2][i];
      ab1[4 + i] = (__bf16)xc[3][i];
    }
    // prefetch tile mt+2 into the buffer just freed (2 iterations of slack)
    if (pf) {
      int tn = (mt + 2) * 16 + r;
      loadA(behB, tn, kb, xp);
      mpv = (tn < T_LEN) ? (boolmask ? (int)maskB8[tn] : maskB32[tn]) : 0;
    }

    // ---- layer 1 (swapped: D[j][t]), bias via MFMA C-in ----
    bf16x4 a2f[4];
#pragma unroll
    for (int jt = 0; jt < 4; ++jt) {
      f32x4 acc = MFMA32(A1[jt][0], ab0, bj4[jt]);
      acc = MFMA32(A1[jt][1], ab1, acc);
#pragma unroll
      for (int i = 0; i < 4; ++i) {
        float h = acc[i];
        h = (h >= 0.f) ? h : al1 * h;
        a2f[jt][i] = (__bf16)h;
      }
    }

    // ---- layer 2: 8x mfma 16x16x16, bias via C-init ----
    f32x4 acc20 = cinit0, acc21 = cinit1;
#pragma unroll
    for (int c = 0; c < 4; ++c) acc20 = MFMA16(a2f[c], B2f[c], acc20);
#pragma unroll
    for (int c = 0; c < 4; ++c) acc21 = MFMA16(a2f[c], B2f[4 + c], acc21);

    // ---- layer 3 dot + reduce over j2 (r-lanes) ----
    f32x4 q;
#pragma unroll
    for (int i = 0; i < 4; ++i) {
      float h0 = acc20[i]; h0 = (h0 >= 0.f) ? h0 : al2 * h0;
      float h1 = acc21[i]; h1 = (h1 >= 0.f) ? h1 : al2 * h1;
      q[i] = h0 * w3v0 + h1 * w3v1;
    }
#pragma unroll
    for (int off = 1; off < 16; off <<= 1)
#pragma unroll
      for (int i = 0; i < 4; ++i) q[i] += __shfl_xor(q[i], off);

    // route logit for t = mt*16 + r to this lane
    const int srcl = (r >> 2) << 4;
    float f0 = __shfl(q[0], srcl);
    float f1 = __shfl(q[1], srcl);
    float f2 = __shfl(q[2], srcl);
    float f3 = __shfl(q[3], srcl);
    float q01 = (r & 1) ? f1 : f0;
    float q23 = (r & 1) ? f3 : f2;
    float qt  = (r & 2) ? q23 : q01;

    // ---- per-lane online softmax (defer-max, threshold 8) ----
    const bool valid = ((mt * 16 + r) < T_LEN) && (mcv != 0);
    float lvt = valid ? qt : -__builtin_inff();
    if (lvt > mrun + 8.f) {          // per-lane predicated; rare after warm-up
      float fs = __expf(mrun - lvt); // mrun=-inf -> 0 (zeroes empty state)
      srun *= fs;
#pragma unroll
      for (int i = 0; i < 4; ++i) { o0[i] *= fs; o1[i] *= fs; o2[i] *= fs; o3[i] *= fs; }
      mrun = lvt;
    }
    float et = valid ? __expf(lvt - mrun) : 0.f;
    srun += et;
#pragma unroll
    for (int i = 0; i < 4; ++i) {
      o0[i] += et * (float)ab0[i];
      o1[i] += et * (float)ab0[4 + i];
      o2[i] += et * (float)ab1[i];
      o3[i] += et * (float)ab1[4 + i];
    }
  };

#pragma unroll 1
  for (int mt = 0; mt < MT - 1; mt += 2) {
    step(xa, ma, mt,     xa, ma, mt + 2 < MT);
    step(xb, mb, mt + 1, xb, mb, mt + 3 < MT);
  }
  step(xa, ma, MT - 1, xa, ma, false);   // mt = 12

  // ---- epilogue: merge per-lane softmax states across r ----
  float M = mrun;
#pragma unroll
  for (int off = 1; off < 16; off <<= 1) M = fmaxf(M, __shfl_xor(M, off));
  {
    float fac = __expf(mrun - M);   // lane never valid -> mrun=-inf -> 0
    srun *= fac;
#pragma unroll
    for (int i = 0; i < 4; ++i) { o0[i] *= fac; o1[i] *= fac; o2[i] *= fac; o3[i] *= fac; }
  }
#pragma unroll
  for (int off = 1; off < 16; off <<= 1) {
#pragma unroll
    for (int i = 0; i < 4; ++i) {
      o0[i] += __shfl_xor(o0[i], off);
      o1[i] += __shfl_xor(o1[i], off);
      o2[i] += __shfl_xor(o2[i], off);
      o3[i] += __shfl_xor(o3[i], off);
    }
    srun += __shfl_xor(srun, off);
  }
  if (r == 0) {
    float inv = 1.f / srun;
    float* po = outG + (size_t)b * 64 + kb;
#pragma unroll
    for (int i = 0; i < 4; ++i) {
      o0[i] *= inv; o1[i] *= inv; o2[i] *= inv; o3[i] *= inv;
    }
    *(f32x4*)(po)      = o0;
    *(f32x4*)(po + 4)  = o1;
    *(f32x4*)(po + 32) = o2;
    *(f32x4*)(po + 36) = o3;
  }
}

extern "C" void kernel_launch(void* const* d_in, const int* in_sizes, int n_in,
                              void* d_out, int out_size, void* d_ws, size_t ws_size,
                              hipStream_t stream) {
  (void)n_in; (void)ws_size; (void)out_size;
  const float* beh  = (const float*)d_in[0];
  const float* cand = (const float*)d_in[1];
  const int*   mask = (const int*)d_in[2];
  const float* W1   = (const float*)d_in[3];
  const float* b1   = (const float*)d_in[4];
  const float* a1   = (const float*)d_in[5];
  const float* W2   = (const float*)d_in[6];
  const float* b2   = (const float*)d_in[7];
  const float* a2   = (const float*)d_in[8];
  const float* W3   = (const float*)d_in[9];
  // d_in[10] (b3): uniform additive bias cancels in softmax

  unsigned char* ws = (unsigned char*)d_ws;
  prep_kernel<<<16, 256, 0, stream>>>(W1, W2, ws);

  int B = in_sizes[1] / 64;   // 4096
  int grid = B / 4;           // one wave per batch row
  lau_kernel<<<grid, 256, 0, stream>>>(beh, cand, mask, b1, a1, b2, a2, W3,
                                       ws, (float*)d_out);
}

// Round 6
// 60.642 us; speedup vs baseline: 1.9696x; 1.5252x over previous
//
#include <hip/hip_runtime.h>
#include <hip/hip_bf16.h>

#define T_LEN   200
#define NTILES  13     // ceil(200/16)
#define H0      7      // tiles handled by half 0 (half 1 gets 6)

typedef __bf16 bf16x8 __attribute__((ext_vector_type(8)));
typedef __bf16 bf16x4 __attribute__((ext_vector_type(4)));
typedef float  f32x4  __attribute__((ext_vector_type(4)));

#if __has_builtin(__builtin_amdgcn_mfma_f32_16x16x16_bf16)
#define MFMA16(a, b, c) __builtin_amdgcn_mfma_f32_16x16x16_bf16((a), (b), (c), 0, 0, 0)
#elif __has_builtin(__builtin_amdgcn_mfma_f32_16x16x16bf16_1k)
#define MFMA16(a, b, c) __builtin_amdgcn_mfma_f32_16x16x16bf16_1k((a), (b), (c), 0, 0, 0)
#else
static __device__ __forceinline__ f32x4 mfma16_asm(bf16x4 a, bf16x4 b, f32x4 c) {
  asm("v_mfma_f32_16x16x16_bf16 %0, %1, %2, %0" : "+v"(c) : "v"(a), "v"(b));
  return c;
}
#define MFMA16(a, b, c) mfma16_asm((a), (b), (c))
#endif

#define MFMA32(a, b, c) __builtin_amdgcn_mfma_f32_16x16x32_bf16((a), (b), (c), 0, 0, 0)

// LDS ~20 KB -> 7 blocks/CU by LDS; weights staged once, shared by both rows.
struct __align__(16) Smem {
  unsigned char w1ac[64 * 144];   // [j][d] bf16: W1a+W1c (stride 144B)
  unsigned char w1d [64 * 144];   // [j][d] bf16: W1d
  float biasL[2][64];             // per-row bias1eff (f32 exact)
  float mO[2][2][64];             // [row][half][col] merged o
  float mM[2][2];                 // [row][half] running max
  float mS[2][2];                 // [row][half] running sum
};

__device__ __forceinline__ void loadA(const float* __restrict__ behB, int t, int kb,
                                      f32x4 (&x)[4]) {
  if (t < T_LEN) {
    const float* p = behB + (size_t)t * 64 + kb;
    x[0] = *(const f32x4*)p;
    x[1] = *(const f32x4*)(p + 4);
    x[2] = *(const f32x4*)(p + 32);
    x[3] = *(const f32x4*)(p + 36);
  } else {
    x[0] = f32x4{0.f, 0.f, 0.f, 0.f};
    x[1] = f32x4{0.f, 0.f, 0.f, 0.f};
    x[2] = f32x4{0.f, 0.f, 0.f, 0.f};
    x[3] = f32x4{0.f, 0.f, 0.f, 0.f};
  }
}

__global__ __launch_bounds__(256, 3) void lau_kernel(
    const float* __restrict__ behG, const float* __restrict__ candG,
    const int*  __restrict__ maskG,
    const float* __restrict__ W1g, const float* __restrict__ b1g, const float* __restrict__ a1g,
    const float* __restrict__ W2g, const float* __restrict__ b2g, const float* __restrict__ a2g,
    const float* __restrict__ W3g,
    float* __restrict__ outG)
{
  __shared__ Smem s;
  const int tid  = threadIdx.x;
  const int lane = tid & 63;
  const int wv   = tid >> 6;
  const int row  = wv >> 1;          // 0..1  (2 rows per block)
  const int half = wv & 1;           // 0..1  (2 waves per row, T-split)
  const int b    = blockIdx.x * 2 + row;
  const int r    = lane & 15;
  const int g    = lane >> 4;
  const int kb   = g * 8;

  // ---- cooperative weight staging (batch-independent, shared by both rows) ----
  for (int idx = tid; idx < 4096; idx += 256) {
    int j = idx & 63, d = idx >> 6;            // consecutive j -> coalesced
    float ac = W1g[d * 64 + j] + W1g[(128 + d) * 64 + j];
    float dd = W1g[(192 + d) * 64 + j];
    *(__bf16*)(s.w1ac + j * 144 + d * 2) = (__bf16)ac;
    *(__bf16*)(s.w1d  + j * 144 + d * 2) = (__bf16)dd;
  }

  const float* candB = candG + (size_t)b * 64;

  // ---- per-row exact f32 bias: b1 + cand @ (W1b - W1c)  (one wave per row) ----
  if (half == 0) {
    float biasv = b1g[lane];
#pragma unroll 8
    for (int d = 0; d < 64; ++d) {
      float wd = W1g[(64 + d) * 64 + lane] - W1g[(128 + d) * 64 + lane];
      biasv += candB[d] * wd;
    }
    s.biasL[row][lane] = biasv;
  }
  __syncthreads();

  const bool boolmask = (__ballot(((const unsigned int*)maskG)[lane] > 1u) != 0ull);

  // cand chunks for this lane's d-columns
  const f32x4 c0a = *(const f32x4*)(candB + kb);
  const f32x4 c0b = *(const f32x4*)(candB + kb + 4);
  const f32x4 c1a = *(const f32x4*)(candB + kb + 32);
  const f32x4 c1b = *(const f32x4*)(candB + kb + 36);

  // loop-invariant layer-1 A-fragments: W1eff^T = (W1a+W1c) + cand_d * W1d
  bf16x8 A1[4][2];
#pragma unroll
  for (int f = 0; f < 8; ++f) {
    const int jt = f >> 1, kc = f & 1;
    const int rowoff = (jt * 16 + r) * 144 + kc * 64 + g * 16;
    bf16x8 ac = *(const bf16x8*)(s.w1ac + rowoff);
    bf16x8 dd = *(const bf16x8*)(s.w1d  + rowoff);
    f32x4 cA = kc ? c1a : c0a;
    f32x4 cB = kc ? c1b : c0b;
    bf16x8 o;
#pragma unroll
    for (int e = 0; e < 4; ++e) {
      o[e]     = (__bf16)((float)ac[e]     + cA[e] * (float)dd[e]);
      o[4 + e] = (__bf16)((float)ac[4 + e] + cB[e] * (float)dd[4 + e]);
    }
    A1[jt][kc] = o;
  }

  // layer-2 B fragments from global (W2 is L1-resident, 8 KB)
  bf16x4 B2f[8];
#pragma unroll
  for (int f = 0; f < 8; ++f) {
    const int nt = f >> 2, c = f & 3;
#pragma unroll
    for (int i = 0; i < 4; ++i)
      B2f[f][i] = (__bf16)W2g[(c * 16 + g * 4 + i) * 32 + nt * 16 + r];
  }

  // per-lane bias rows for layer-1 C-init
  f32x4 bj4[4];
#pragma unroll
  for (int jt = 0; jt < 4; ++jt)
#pragma unroll
    for (int i = 0; i < 4; ++i)
      bj4[jt][i] = s.biasL[row][jt * 16 + g * 4 + i];

  const float al1 = a1g[0];
  const float al2 = a2g[0];
  const float b2v0 = b2g[r],  b2v1 = b2g[16 + r];
  const float w3v0 = W3g[r],  w3v1 = W3g[16 + r];
  const f32x4 cinit0 = {b2v0, b2v0, b2v0, b2v0};
  const f32x4 cinit1 = {b2v1, b2v1, b2v1, b2v1};

  const float* behB = behG + (size_t)b * T_LEN * 64;
  const unsigned char* maskB8 = (const unsigned char*)maskG + (size_t)b * T_LEN;
  const int* maskB32 = maskG + (size_t)b * T_LEN;

  // this wave's tile range
  const int mt0 = half ? H0 : 0;
  const int mtN = half ? (NTILES - H0) : H0;

  float mrun = -__builtin_inff();   // wave-uniform
  float srun = 0.f;
  f32x4 o0 = {0,0,0,0}, o1 = {0,0,0,0}, o2 = {0,0,0,0}, o3 = {0,0,0,0};

  f32x4 xc[4], xn[4];
  {
    int t0 = mt0 * 16 + r;
    loadA(behB, t0, kb, xc);
  }
  int mc = 0, mn = 0;
  {
    int t0 = mt0 * 16 + r;
    mc = (t0 < T_LEN) ? (boolmask ? (int)maskB8[t0] : maskB32[t0]) : 0;
  }

#pragma unroll 1
  for (int it = 0; it < mtN; ++it) {
    const int mt = mt0 + it;
    // depth-1 prefetch
    if (it + 1 < mtN) {
      int tn = (mt + 1) * 16 + r;
      loadA(behB, tn, kb, xn);
      mn = (tn < T_LEN) ? (boolmask ? (int)maskB8[tn] : maskB32[tn]) : 0;
    }

    // bf16 B-fragments for layer 1
    bf16x8 ab0, ab1;
#pragma unroll
    for (int i = 0; i < 4; ++i) {
      ab0[i]     = (__bf16)xc[0][i];
      ab0[4 + i] = (__bf16)xc[1][i];
      ab1[i]     = (__bf16)xc[2][i];
      ab1[4 + i] = (__bf16)xc[3][i];
    }

    // ---- layer 1 (swapped: D[j][t]), bias via MFMA C-in ----
    bf16x4 a2f[4];
#pragma unroll
    for (int jt = 0; jt < 4; ++jt) {
      f32x4 acc = MFMA32(A1[jt][0], ab0, bj4[jt]);
      acc = MFMA32(A1[jt][1], ab1, acc);
#pragma unroll
      for (int i = 0; i < 4; ++i) {
        float h = acc[i];
        h = (h >= 0.f) ? h : al1 * h;
        a2f[jt][i] = (__bf16)h;
      }
    }

    // ---- layer 2: 8x mfma 16x16x16, bias via C-init ----
    f32x4 acc20 = cinit0, acc21 = cinit1;
#pragma unroll
    for (int c = 0; c < 4; ++c) acc20 = MFMA16(a2f[c], B2f[c], acc20);
#pragma unroll
    for (int c = 0; c < 4; ++c) acc21 = MFMA16(a2f[c], B2f[4 + c], acc21);

    // ---- layer 3 dot + reduce over j2 ----
    f32x4 q;
#pragma unroll
    for (int i = 0; i < 4; ++i) {
      float h0 = acc20[i]; h0 = (h0 >= 0.f) ? h0 : al2 * h0;
      float h1 = acc21[i]; h1 = (h1 >= 0.f) ? h1 : al2 * h1;
      q[i] = h0 * w3v0 + h1 * w3v1;
    }
#pragma unroll
    for (int off = 1; off < 16; off <<= 1)
#pragma unroll
      for (int i = 0; i < 4; ++i) q[i] += __shfl_xor(q[i], off);
    // q[i] at group g = logit[t = mt*16 + g*4 + i], replicated across r

    // route logit for t = mt*16 + r to this lane
    const int srcl = (r >> 2) << 4;
    float f0 = __shfl(q[0], srcl);
    float f1 = __shfl(q[1], srcl);
    float f2 = __shfl(q[2], srcl);
    float f3 = __shfl(q[3], srcl);
    float q01 = (r & 1) ? f1 : f0;
    float q23 = (r & 1) ? f3 : f2;
    float qt  = (r & 2) ? q23 : q01;

    const bool valid = ((mt * 16 + r) < T_LEN) && (mc != 0);
    float lvt = valid ? qt : -__builtin_inff();
    float tm = lvt;
#pragma unroll
    for (int off = 1; off < 16; off <<= 1) tm = fmaxf(tm, __shfl_xor(tm, off));

    // defer-max (wave-uniform): rescale only when tile max moved by > 8
    if (tm > mrun + 8.f) {
      float fs = __expf(mrun - tm);   // mrun=-inf -> 0 (zeroes empty state)
      srun *= fs;
#pragma unroll
      for (int i = 0; i < 4; ++i) { o0[i] *= fs; o1[i] *= fs; o2[i] *= fs; o3[i] *= fs; }
      mrun = tm;
    }
    float et = valid ? __expf(lvt - mrun) : 0.f;
    srun += et;
#pragma unroll
    for (int i = 0; i < 4; ++i) {
      o0[i] += et * xc[0][i];
      o1[i] += et * xc[1][i];
      o2[i] += et * xc[2][i];
      o3[i] += et * xc[3][i];
    }

#pragma unroll
    for (int i = 0; i < 4; ++i) xc[i] = xn[i];
    mc = mn;
  }

  // ---- per-wave reduce over r, publish (m, s, o) for the merge ----
#pragma unroll
  for (int off = 1; off < 16; off <<= 1) {
#pragma unroll
    for (int i = 0; i < 4; ++i) {
      o0[i] += __shfl_xor(o0[i], off);
      o1[i] += __shfl_xor(o1[i], off);
      o2[i] += __shfl_xor(o2[i], off);
      o3[i] += __shfl_xor(o3[i], off);
    }
    srun += __shfl_xor(srun, off);
  }
  if (r == 0) {
    *(f32x4*)&s.mO[row][half][kb]      = o0;
    *(f32x4*)&s.mO[row][half][kb + 4]  = o1;
    *(f32x4*)&s.mO[row][half][kb + 32] = o2;
    *(f32x4*)&s.mO[row][half][kb + 36] = o3;
  }
  if (lane == 0) { s.mM[row][half] = mrun; s.mS[row][half] = srun; }
  __syncthreads();

  // ---- cross-wave merge: wave 0 -> row 0, wave 1 -> row 1 ----
  if (wv < 2) {
    const int rw = wv;
    const int bb = blockIdx.x * 2 + rw;
    float m0 = s.mM[rw][0], m1 = s.mM[rw][1];
    float M  = fmaxf(m0, m1);
    float e0 = __expf(m0 - M), e1 = __expf(m1 - M);   // empty half -> exp(-inf)=0
    float denom = s.mS[rw][0] * e0 + s.mS[rw][1] * e1;
    float inv = 1.f / denom;
    float val = (s.mO[rw][0][lane] * e0 + s.mO[rw][1][lane] * e1) * inv;
    outG[(size_t)bb * 64 + lane] = val;
  }
}

extern "C" void kernel_launch(void* const* d_in, const int* in_sizes, int n_in,
                              void* d_out, int out_size, void* d_ws, size_t ws_size,
                              hipStream_t stream) {
  (void)n_in; (void)d_ws; (void)ws_size; (void)out_size;
  const float* beh  = (const float*)d_in[0];
  const float* cand = (const float*)d_in[1];
  const int*   mask = (const int*)d_in[2];
  const float* W1   = (const float*)d_in[3];
  const float* b1   = (const float*)d_in[4];
  const float* a1   = (const float*)d_in[5];
  const float* W2   = (const float*)d_in[6];
  const float* b2   = (const float*)d_in[7];
  const float* a2   = (const float*)d_in[8];
  const float* W3   = (const float*)d_in[9];
  // d_in[10] (b3): uniform additive bias cancels in softmax

  int B = in_sizes[1] / 64;   // 4096
  int grid = B / 2;           // 2 rows per block, 2 waves per row
  lau_kernel<<<grid, 256, 0, stream>>>(beh, cand, mask, W1, b1, a1, W2, b2, a2, W3,
                                       (float*)d_out);
}

// Round 7
// 58.613 us; speedup vs baseline: 2.0378x; 1.0346x over previous
//
#include <hip/hip_runtime.h>
#include <hip/hip_bf16.h>

#define T_LEN   200
#define NTILES  13     // ceil(200/16)

typedef __bf16 bf16x8 __attribute__((ext_vector_type(8)));
typedef __bf16 bf16x4 __attribute__((ext_vector_type(4)));
typedef float  f32x4  __attribute__((ext_vector_type(4)));

#if __has_builtin(__builtin_amdgcn_mfma_f32_16x16x16_bf16)
#define MFMA16(a, b, c) __builtin_amdgcn_mfma_f32_16x16x16_bf16((a), (b), (c), 0, 0, 0)
#elif __has_builtin(__builtin_amdgcn_mfma_f32_16x16x16bf16_1k)
#define MFMA16(a, b, c) __builtin_amdgcn_mfma_f32_16x16x16bf16_1k((a), (b), (c), 0, 0, 0)
#else
static __device__ __forceinline__ f32x4 mfma16_asm(bf16x4 a, bf16x4 b, f32x4 c) {
  asm("v_mfma_f32_16x16x16_bf16 %0, %1, %2, %0" : "+v"(c) : "v"(a), "v"(b));
  return c;
}
#define MFMA16(a, b, c) mfma16_asm((a), (b), (c))
#endif

#define MFMA32(a, b, c) __builtin_amdgcn_mfma_f32_16x16x32_bf16((a), (b), (c), 0, 0, 0)

// LDS ~19.5 KB (not occupancy-limiting). Weights staged once per block.
struct __align__(16) Smem {
  unsigned char w1ac[64 * 144];   // [j][d] bf16: W1a+W1c (stride 144B, conflict-free frags)
  unsigned char w1d [64 * 144];   // [j][d] bf16: W1d
  float biasL[4][64];             // per-wave(row) exact f32 bias1eff
};

__device__ __forceinline__ void loadA(const float* __restrict__ behB, int t, int kb,
                                      f32x4 (&x)[4]) {
  if (t < T_LEN) {
    const float* p = behB + (size_t)t * 64 + kb;
    x[0] = *(const f32x4*)p;
    x[1] = *(const f32x4*)(p + 4);
    x[2] = *(const f32x4*)(p + 32);
    x[3] = *(const f32x4*)(p + 36);
  } else {
    x[0] = f32x4{0.f, 0.f, 0.f, 0.f};
    x[1] = f32x4{0.f, 0.f, 0.f, 0.f};
    x[2] = f32x4{0.f, 0.f, 0.f, 0.f};
    x[3] = f32x4{0.f, 0.f, 0.f, 0.f};
  }
}

__global__ __launch_bounds__(256, 3) void lau_kernel(
    const float* __restrict__ behG, const float* __restrict__ candG,
    const int*  __restrict__ maskG,
    const float* __restrict__ W1g, const float* __restrict__ b1g, const float* __restrict__ a1g,
    const float* __restrict__ W2g, const float* __restrict__ b2g, const float* __restrict__ a2g,
    const float* __restrict__ W3g,
    float* __restrict__ outG)
{
  __shared__ Smem s;
  const int tid  = threadIdx.x;
  const int lane = tid & 63;
  const int wv   = tid >> 6;
  const int b    = blockIdx.x * 4 + wv;   // one wave per batch row
  const int r    = lane & 15;
  const int g    = lane >> 4;
  const int kb   = g * 8;

  const float* candB = candG + (size_t)b * 64;

  // ---- cooperative weight staging (batch-independent) ----
  for (int idx = tid; idx < 4096; idx += 256) {
    int j = idx & 63, d = idx >> 6;            // consecutive j -> coalesced
    float ac = W1g[d * 64 + j] + W1g[(128 + d) * 64 + j];
    float dd = W1g[(192 + d) * 64 + j];
    *(__bf16*)(s.w1ac + j * 144 + d * 2) = (__bf16)ac;
    *(__bf16*)(s.w1d  + j * 144 + d * 2) = (__bf16)dd;
  }
  // per-row exact f32 bias: b1 + cand @ (W1b - W1c)  (each wave does its own row)
  {
    float biasv = b1g[lane];
#pragma unroll 8
    for (int d = 0; d < 64; ++d) {
      float wd = W1g[(64 + d) * 64 + lane] - W1g[(128 + d) * 64 + lane];
      biasv += candB[d] * wd;
    }
    s.biasL[wv][lane] = biasv;
  }
  __syncthreads();
  // ---- waves fully independent below ----

  const bool boolmask = (__ballot(((const unsigned int*)maskG)[lane] > 1u) != 0ull);

  // cand chunks for this lane's d-columns
  const f32x4 c0a = *(const f32x4*)(candB + kb);
  const f32x4 c0b = *(const f32x4*)(candB + kb + 4);
  const f32x4 c1a = *(const f32x4*)(candB + kb + 32);
  const f32x4 c1b = *(const f32x4*)(candB + kb + 36);

  // loop-invariant layer-1 A-fragments: W1eff^T = (W1a+W1c) + cand_d * W1d
  bf16x8 A1[4][2];
#pragma unroll
  for (int f = 0; f < 8; ++f) {
    const int jt = f >> 1, kc = f & 1;
    const int rowoff = (jt * 16 + r) * 144 + kc * 64 + g * 16;
    bf16x8 ac = *(const bf16x8*)(s.w1ac + rowoff);
    bf16x8 dd = *(const bf16x8*)(s.w1d  + rowoff);
    f32x4 cA = kc ? c1a : c0a;
    f32x4 cB = kc ? c1b : c0b;
    bf16x8 o;
#pragma unroll
    for (int e = 0; e < 4; ++e) {
      o[e]     = (__bf16)((float)ac[e]     + cA[e] * (float)dd[e]);
      o[4 + e] = (__bf16)((float)ac[4 + e] + cB[e] * (float)dd[4 + e]);
    }
    A1[jt][kc] = o;
  }

  // layer-2 weight fragments, SAME packing as before, but now used as the
  // A-operand (first arg): W2f[nt*4+c][i] = W2[c*16 + g*4 + i][nt*16 + r]
  bf16x4 W2f[8];
#pragma unroll
  for (int f = 0; f < 8; ++f) {
    const int nt = f >> 2, c = f & 3;
#pragma unroll
    for (int i = 0; i < 4; ++i)
      W2f[f][i] = (__bf16)W2g[(c * 16 + g * 4 + i) * 32 + nt * 16 + r];
  }

  // per-lane bias rows for layer-1 C-init: bias[j = jt*16 + g*4 + i]
  f32x4 bj4[4];
#pragma unroll
  for (int jt = 0; jt < 4; ++jt)
#pragma unroll
    for (int i = 0; i < 4; ++i)
      bj4[jt][i] = s.biasL[wv][jt * 16 + g * 4 + i];

  const float al1 = a1g[0];
  const float al2 = a2g[0];
  // j2-indexed constants (j2 = nt*16 + g*4 + i): vector loads
  const f32x4 cinit0 = *(const f32x4*)(b2g + g * 4);
  const f32x4 cinit1 = *(const f32x4*)(b2g + 16 + g * 4);
  const f32x4 w3f0   = *(const f32x4*)(W3g + g * 4);
  const f32x4 w3f1   = *(const f32x4*)(W3g + 16 + g * 4);

  const float* behB = behG + (size_t)b * T_LEN * 64;
  const unsigned char* maskB8 = (const unsigned char*)maskG + (size_t)b * T_LEN;
  const int* maskB32 = maskG + (size_t)b * T_LEN;

  // per-lane online-softmax state (lane owns t = mt*16 + r, same across g)
  float mrun = -__builtin_inff();
  float srun = 0.f;
  f32x4 o0 = {0,0,0,0}, o1 = {0,0,0,0}, o2 = {0,0,0,0}, o3 = {0,0,0,0};

  f32x4 xc[4];
  loadA(behB, r, kb, xc);
  int mc = boolmask ? (int)maskB8[r] : maskB32[r];

#pragma unroll 1
  for (int mt = 0; mt < NTILES; ++mt) {
    // convert current tile to bf16 fragments, then reuse xc for prefetch
    bf16x8 ab0, ab1;
#pragma unroll
    for (int i = 0; i < 4; ++i) {
      ab0[i]     = (__bf16)xc[0][i];
      ab0[4 + i] = (__bf16)xc[1][i];
      ab1[i]     = (__bf16)xc[2][i];
      ab1[4 + i] = (__bf16)xc[3][i];
    }
    const int mcur = mc;
    if (mt + 1 < NTILES) {
      int tn = (mt + 1) * 16 + r;
      loadA(behB, tn, kb, xc);
      mc = (tn < T_LEN) ? (boolmask ? (int)maskB8[tn] : maskB32[tn]) : 0;
    }

    // ---- layer 1 (swapped: D1[j][t]), bias via MFMA C-in ----
    bf16x4 a2f[4];
#pragma unroll
    for (int jt = 0; jt < 4; ++jt) {
      f32x4 acc = MFMA32(A1[jt][0], ab0, bj4[jt]);
      acc = MFMA32(A1[jt][1], ab1, acc);
#pragma unroll
      for (int i = 0; i < 4; ++i) {
        float h = acc[i];
        h = (h >= 0.f) ? h : al1 * h;
        a2f[jt][i] = (__bf16)h;
      }
    }

    // ---- layer 2 SWAPPED: D2[j2][t] = W2^T · h1^T  (W2f as A, a2f as B) ----
    f32x4 acc20 = cinit0, acc21 = cinit1;
#pragma unroll
    for (int c = 0; c < 4; ++c) acc20 = MFMA16(W2f[c],     a2f[c], acc20);
#pragma unroll
    for (int c = 0; c < 4; ++c) acc21 = MFMA16(W2f[4 + c], a2f[c], acc21);

    // ---- layer 3: in-lane dot over this lane's 8 j2's, then 2-step g-reduce ----
    float partial = 0.f;
#pragma unroll
    for (int i = 0; i < 4; ++i) {
      float h0 = acc20[i]; h0 = (h0 >= 0.f) ? h0 : al2 * h0;
      float h1 = acc21[i]; h1 = (h1 >= 0.f) ? h1 : al2 * h1;
      partial += h0 * w3f0[i] + h1 * w3f1[i];
    }
    partial += __shfl_xor(partial, 16);
    partial += __shfl_xor(partial, 32);
    // partial = logit[t = mt*16 + r], replicated across g

    // ---- per-lane online softmax (defer-max, threshold 8) ----
    const bool valid = ((mt * 16 + r) < T_LEN) && (mcur != 0);
    float lvt = valid ? partial : -__builtin_inff();
    if (lvt > mrun + 8.f) {          // rare after first tile
      float fs = __expf(mrun - lvt); // mrun=-inf -> 0 (zeroes empty state)
      srun *= fs;
#pragma unroll
      for (int i = 0; i < 4; ++i) { o0[i] *= fs; o1[i] *= fs; o2[i] *= fs; o3[i] *= fs; }
      mrun = lvt;
    }
    float et = valid ? __expf(lvt - mrun) : 0.f;
    srun += et;
#pragma unroll
    for (int i = 0; i < 4; ++i) {
      o0[i] += et * (float)ab0[i];
      o1[i] += et * (float)ab0[4 + i];
      o2[i] += et * (float)ab1[i];
      o3[i] += et * (float)ab1[4 + i];
    }
  }

  // ---- epilogue: merge the 16 per-lane states across r ----
  float M = mrun;
#pragma unroll
  for (int off = 1; off < 16; off <<= 1) M = fmaxf(M, __shfl_xor(M, off));
  {
    float fac = __expf(mrun - M);   // never-valid lane: exp(-inf)=0
    srun *= fac;
#pragma unroll
    for (int i = 0; i < 4; ++i) { o0[i] *= fac; o1[i] *= fac; o2[i] *= fac; o3[i] *= fac; }
  }
#pragma unroll
  for (int off = 1; off < 16; off <<= 1) {
#pragma unroll
    for (int i = 0; i < 4; ++i) {
      o0[i] += __shfl_xor(o0[i], off);
      o1[i] += __shfl_xor(o1[i], off);
      o2[i] += __shfl_xor(o2[i], off);
      o3[i] += __shfl_xor(o3[i], off);
    }
    srun += __shfl_xor(srun, off);
  }
  if (r == 0) {
    float inv = 1.f / srun;
    float* po = outG + (size_t)b * 64 + kb;
#pragma unroll
    for (int i = 0; i < 4; ++i) {
      o0[i] *= inv; o1[i] *= inv; o2[i] *= inv; o3[i] *= inv;
    }
    *(f32x4*)(po)      = o0;
    *(f32x4*)(po + 4)  = o1;
    *(f32x4*)(po + 32) = o2;
    *(f32x4*)(po + 36) = o3;
  }
}

extern "C" void kernel_launch(void* const* d_in, const int* in_sizes, int n_in,
                              void* d_out, int out_size, void* d_ws, size_t ws_size,
                              hipStream_t stream) {
  (void)n_in; (void)d_ws; (void)ws_size; (void)out_size;
  const float* beh  = (const float*)d_in[0];
  const float* cand = (const float*)d_in[1];
  const int*   mask = (const int*)d_in[2];
  const float* W1   = (const float*)d_in[3];
  const float* b1   = (const float*)d_in[4];
  const float* a1   = (const float*)d_in[5];
  const float* W2   = (const float*)d_in[6];
  const float* b2   = (const float*)d_in[7];
  const float* a2   = (const float*)d_in[8];
  const float* W3   = (const float*)d_in[9];
  // d_in[10] (b3): uniform additive bias cancels in softmax

  int B = in_sizes[1] / 64;   // 4096
  int grid = B / 4;           // one wave per batch row
  lau_kernel<<<grid, 256, 0, stream>>>(beh, cand, mask, W1, b1, a1, W2, b2, a2, W3,
                                       (float*)d_out);
}